// Round 1
// 131.824 us; speedup vs baseline: 1.0355x; 1.0355x over previous
//
#include <hip/hip_runtime.h>

// Problem shape (fixed; established r6/r7/r10/r11 of prior session):
//   d_in[0]: (1024, 256) int32  ids in [0, 30522)
//   d_in[1]: (1024, 256) f32    weights uniform [0,1)
//   d_out:   (1024, 30522) f32  -- value = bf16(RN-even) of scatter-max of the
//            per-token weight into its vocab slot, 0 baseline, stored as f32.
//
// This round: FUSED single kernel. The old version memset 500 MB (out_size was
// bytes, not elements -- WRITE_SIZE=488,352 KB proved a 4x over-fill, ~57 us
// dead) and then did 262K scattered global atomics over a cold 125 MB range
// (~60 us). Here each block owns one (row, vocab-half): zero a 61 KB LDS
// table, LDS-atomicMax the row's 256 rounded weights into it, stream the half
// out coalesced. Zero baseline comes from the LDS zeroing; no memset, no
// global atomics, every output byte written exactly once (125 MB).
#define VOCAB 30522
#define SEQ   256
#define CHUNK 15264   // 2 chunks/row; chunk0 = 15264 slots, chunk1 = 15258

// bf16 RN-even of a nonneg f32, re-expanded to f32 bits. Nonneg IEEE bit
// patterns are order-isomorphic to values and RN-even is monotone on nonneg
// inputs, so round-then-max == max-then-round (bit-exact vs reference).
__device__ __forceinline__ unsigned bf16_bits(float w) {
    const unsigned u = __float_as_uint(w);
    return ((u + 0x7FFFu + ((u >> 16) & 1u)) >> 16) << 16;
}

extern "C" __global__ __launch_bounds__(256)
void TargetEncoder_532575944857_kernel(const int* __restrict__ ids,
                                       const float* __restrict__ ws,
                                       unsigned int* __restrict__ out,
                                       int n_rows) {
    __shared__ unsigned int tab[CHUNK];   // 61,056 B -> 2 blocks/CU (160 KB)

    const int blk  = blockIdx.x;
    const int b    = blk >> 1;            // row
    const int c    = blk & 1;             // vocab half
    const int t    = threadIdx.x;
    const int base = c * CHUNK;
    const int lim  = c ? (VOCAB - CHUNK) : CHUNK;   // 15258 : 15264

    if (b >= n_rows) return;

    // Phase 1: zero the LDS table (this IS the output's 0 baseline).
    for (int i = t; i < CHUNK; i += 256) tab[i] = 0u;
    __syncthreads();

    // Phase 2: scatter-max this row's 256 tokens into LDS. One token/thread;
    // duplicates resolved by the LDS atomic. Out-of-chunk (and any defensive
    // out-of-range) ids fail the unsigned bound check and are skipped.
    {
        const int    tok = b * SEQ + t;
        const int    id  = ids[tok];
        const unsigned val = bf16_bits(ws[tok]);
        const int    loc = id - base;
        if (val != 0u && (unsigned)loc < (unsigned)lim)
            atomicMax(&tab[loc], val);
    }
    __syncthreads();

    // Phase 3: stream the half-row to global, coalesced uint2 (8 B/lane,
    // 512 B/wave). Row byte offset = b*122088 + c*61056, both % 8 == 0, and
    // lim is even for both halves (15264 / 15258) -> no scalar tail.
    uint2*       dst = (uint2*)(out + (long long)b * VOCAB + base);
    const uint2* src = (const uint2*)tab;
    const int n2 = lim >> 1;              // 7632 : 7629
    for (int j = t; j < n2; j += 256) dst[j] = src[j];
}

extern "C" void kernel_launch(void* const* d_in, const int* in_sizes, int n_in,
                              void* d_out, int out_size, void* d_ws, size_t ws_size,
                              hipStream_t stream) {
    const int*   ids = (const int*)d_in[0];
    const float* ws  = (const float*)d_in[1];
    const int n_tok  = in_sizes[0];        // 262144
    const int n_rows = n_tok / SEQ;        // 1024

    TargetEncoder_532575944857_kernel<<<dim3(n_rows * 2), dim3(256), 0, stream>>>(
        ids, ws, (unsigned int*)d_out, n_rows);
}